// Round 1
// baseline (605.048 us; speedup 1.0000x reference)
//
#include <hip/hip_runtime.h>

#define NN 2048
#define FF 64
#define HH 32
#define OO 32

// ---------------------------------------------------------------------------
// Kernel 1: f_sums[n, o] = sum_f MLP_f(x[n, f])   -> written to workspace
// One wave (64 lanes) per node; lane = feature index. Butterfly-reduce over
// the 64 lanes (features), lane 0 writes the 32 outputs.
// ---------------------------------------------------------------------------
__global__ __launch_bounds__(256) void fsums_kernel(
    const float* __restrict__ x,     // [N,F]
    const float* __restrict__ fW1,   // [F,1,H]
    const float* __restrict__ fb1,   // [F,H]
    const float* __restrict__ fW2,   // [F,H,H]
    const float* __restrict__ fb2,   // [F,H]
    const float* __restrict__ fW3,   // [F,H,O]
    const float* __restrict__ fb3,   // [F,O]
    float* __restrict__ f_sums)      // [N,O]
{
    const int wave = threadIdx.x >> 6;           // 0..3
    const int lane = threadIdx.x & 63;           // = feature f
    const int n = blockIdx.x * 4 + wave;
    const int f = lane;

    const float xv = x[n * FF + f];

    float h1[HH];
#pragma unroll
    for (int h = 0; h < HH; ++h)
        h1[h] = fmaxf(xv * fW1[f * HH + h] + fb1[f * HH + h], 0.f);

    float h2[HH];
#pragma unroll
    for (int g = 0; g < HH; ++g) h2[g] = fb2[f * HH + g];
#pragma unroll
    for (int h = 0; h < HH; ++h) {
        const float a = h1[h];
        const float* __restrict__ w = &fW2[(f * HH + h) * HH];
#pragma unroll
        for (int g = 0; g < HH; ++g) h2[g] += a * w[g];
    }
#pragma unroll
    for (int g = 0; g < HH; ++g) h2[g] = fmaxf(h2[g], 0.f);

    float acc[OO];
#pragma unroll
    for (int o = 0; o < OO; ++o) acc[o] = fb3[f * OO + o];
#pragma unroll
    for (int h = 0; h < HH; ++h) {
        const float a = h2[h];
        const float* __restrict__ w = &fW3[(f * HH + h) * OO];
#pragma unroll
        for (int o = 0; o < OO; ++o) acc[o] += a * w[o];
    }

    // Reduce over the 64 lanes (sum over features)
#pragma unroll
    for (int o = 0; o < OO; ++o) {
        float v = acc[o];
#pragma unroll
        for (int off = 32; off >= 1; off >>= 1)
            v += __shfl_xor(v, off, 64);
        acc[o] = v;
    }

    if (lane == 0) {
#pragma unroll
        for (int o = 0; o < OO; ++o)
            f_sums[n * OO + o] = acc[o];
    }
}

// ---------------------------------------------------------------------------
// Kernel 2: fused rho(d)/norm @ f_sums.
// One block (256 threads) per output row n. Each thread handles 8 m's:
// scalar MLP rho(d[n,m]), divide by norm, accumulate r * f_sums[m, :] into
// per-thread acc[32]. Block-reduce at the end.
// rho weights are wave-uniform -> scalar loads (broadcast), cheap.
// ---------------------------------------------------------------------------
__global__ __launch_bounds__(256) void rho_matmul_kernel(
    const float* __restrict__ dmat,   // [N,N]
    const float* __restrict__ norm,   // [N,N]
    const float* __restrict__ rW1,    // [1,H]
    const float* __restrict__ rb1,    // [H]
    const float* __restrict__ rW2,    // [H,H]
    const float* __restrict__ rb2,    // [H]
    const float* __restrict__ rW3,    // [H,1]
    const float* __restrict__ rb3,    // [1]
    const float* __restrict__ f_sums, // [N,O]
    float* __restrict__ out)          // [N,O]
{
    const int n = blockIdx.x;
    const int t = threadIdx.x;

    float acc[OO];
#pragma unroll
    for (int o = 0; o < OO; ++o) acc[o] = 0.f;

#pragma unroll 1
    for (int m0 = 0; m0 < NN; m0 += 256) {
        const int m = m0 + t;
        const float d = dmat[n * NN + m];

        float h1[HH];
#pragma unroll
        for (int h = 0; h < HH; ++h)
            h1[h] = fmaxf(d * rW1[h] + rb1[h], 0.f);

        float h2[HH];
#pragma unroll
        for (int g = 0; g < HH; ++g) h2[g] = rb2[g];
#pragma unroll
        for (int h = 0; h < HH; ++h) {
            const float a = h1[h];
#pragma unroll
            for (int g = 0; g < HH; ++g) h2[g] += a * rW2[h * HH + g];
        }

        float r = rb3[0];
#pragma unroll
        for (int h = 0; h < HH; ++h)
            r += fmaxf(h2[h], 0.f) * rW3[h];

        r /= norm[n * NN + m];

        const float* __restrict__ fs = &f_sums[m * OO];
#pragma unroll
        for (int o = 0; o < OO; ++o) acc[o] += r * fs[o];
    }

    // ---- block reduction: 256 threads -> 32 outputs ----
    __shared__ float red[4][OO];
    const int wave = t >> 6;
    const int lane = t & 63;

#pragma unroll
    for (int o = 0; o < OO; ++o) {
        float v = acc[o];
#pragma unroll
        for (int off = 32; off >= 1; off >>= 1)
            v += __shfl_xor(v, off, 64);
        acc[o] = v;
    }
    if (lane == 0) {
#pragma unroll
        for (int o = 0; o < OO; ++o) red[wave][o] = acc[o];
    }
    __syncthreads();

    if (t < OO) {
        const float s = red[0][t] + red[1][t] + red[2][t] + red[3][t];
        out[n * OO + t] = s;
    }
}

extern "C" void kernel_launch(void* const* d_in, const int* in_sizes, int n_in,
                              void* d_out, int out_size, void* d_ws, size_t ws_size,
                              hipStream_t stream) {
    const float* x    = (const float*)d_in[0];
    const float* dmat = (const float*)d_in[1];
    const float* norm = (const float*)d_in[2];
    const float* fW1  = (const float*)d_in[3];
    const float* fb1  = (const float*)d_in[4];
    const float* fW2  = (const float*)d_in[5];
    const float* fb2  = (const float*)d_in[6];
    const float* fW3  = (const float*)d_in[7];
    const float* fb3  = (const float*)d_in[8];
    const float* rW1  = (const float*)d_in[9];
    const float* rb1  = (const float*)d_in[10];
    const float* rW2  = (const float*)d_in[11];
    const float* rb2  = (const float*)d_in[12];
    const float* rW3  = (const float*)d_in[13];
    const float* rb3  = (const float*)d_in[14];

    float* out    = (float*)d_out;
    float* f_sums = (float*)d_ws;   // N*O floats = 256 KB

    // Kernel 1: f_sums  (512 blocks x 256 threads = one wave per node)
    fsums_kernel<<<NN / 4, 256, 0, stream>>>(x, fW1, fb1, fW2, fb2, fW3, fb3,
                                             f_sums);

    // Kernel 2: fused rho + normalize + matmul (one block per row)
    rho_matmul_kernel<<<NN, 256, 0, stream>>>(dmat, norm, rW1, rb1, rW2, rb2,
                                              rW3, rb3, f_sums, out);
}

// Round 2
// 171.878 us; speedup vs baseline: 3.5202x; 3.5202x over previous
//
#include <hip/hip_runtime.h>

#define NN 2048
#define FF 64
#define HH 32
#define OO 32

// Workspace layout (bytes):
//   0        : f_sums       [2048*32] f32   (256 KB)
//   262144   : partial      [16*2048*32] f32 (4 MB)
//   4456448  : q_pos        [64*32] f32
//   4464640  : q_neg        [64*32] f32
//   4472832  : qb           [32] f32        (sum_f fb3[f,:])
//   4472960  : cpr          [2] f32         (c_plus, c_minus)
//   4472976  : flags        [2] int         (fb-zero, rb-zero)
#define WS_FSUMS   0
#define WS_PARTIAL 262144
#define WS_QPOS    4456448
#define WS_QNEG    4464640
#define WS_QB      4472832
#define WS_CPR     4472960
#define WS_FLAGS   4472976

#define KSPLIT 16   // K-chunks of 128 m each
#define ROWT   64   // rows per block in rho_fast

// ---------------------------------------------------------------------------
// Precompute: q_pos/q_neg tables, qb, c_plus/c_minus, and zero-bias flags.
// One block, 256 threads.
// ---------------------------------------------------------------------------
__global__ __launch_bounds__(256) void precompute_kernel(
    const float* __restrict__ fW1, const float* __restrict__ fb1,
    const float* __restrict__ fW2, const float* __restrict__ fb2,
    const float* __restrict__ fW3, const float* __restrict__ fb3,
    const float* __restrict__ rW1, const float* __restrict__ rb1,
    const float* __restrict__ rW2, const float* __restrict__ rb2,
    const float* __restrict__ rW3,
    float* __restrict__ q_pos, float* __restrict__ q_neg,
    float* __restrict__ qb, float* __restrict__ cpr,
    int* __restrict__ flags)
{
    __shared__ float vb[2][FF][HH];   // per-feature v vectors (pos/neg)
    __shared__ int sflags[2];

    const int t = threadIdx.x;
    if (t == 0) { sflags[0] = 1; sflags[1] = 1; }
    __syncthreads();

    // ---- phase 1 ----
    if (t < 128) {
        // v_s[f][g] = sum_h clamp_s(fW1[f,h]) * fW2[f,h,g]
        const int f = t & 63;
        const int s = t >> 6;          // 0 = pos, 1 = neg
        float v[HH];
#pragma unroll
        for (int g = 0; g < HH; ++g) v[g] = 0.f;
        for (int h = 0; h < HH; ++h) {
            const float w1 = fW1[f * HH + h];
            const float a = s ? fminf(w1, 0.f) : fmaxf(w1, 0.f);
            const float* __restrict__ w = &fW2[(f * HH + h) * HH];
#pragma unroll
            for (int g = 0; g < HH; ++g) v[g] += a * w[g];
        }
#pragma unroll
        for (int g = 0; g < HH; ++g) vb[s][f][g] = v[g];
    } else if (t < 130) {
        // c_plus / c_minus for rho
        const int s = t - 128;
        float v[HH];
#pragma unroll
        for (int g = 0; g < HH; ++g) v[g] = 0.f;
        for (int h = 0; h < HH; ++h) {
            const float w1 = rW1[h];
            const float a = s ? fminf(w1, 0.f) : fmaxf(w1, 0.f);
#pragma unroll
            for (int g = 0; g < HH; ++g) v[g] += a * rW2[h * HH + g];
        }
        float c = 0.f;
#pragma unroll
        for (int g = 0; g < HH; ++g) {
            const float w = s ? fminf(v[g], 0.f) : fmaxf(v[g], 0.f);
            c += w * rW3[g];
        }
        cpr[s] = c;
    } else if (t >= 160 && t < 192) {
        // qb[o] = sum_f fb3[f,o]
        const int o = t - 160;
        float a = 0.f;
        for (int f = 0; f < FF; ++f) a += fb3[f * OO + o];
        qb[o] = a;
    } else if (t >= 192) {
        // zero-bias scans
        const int i = t - 192;                 // 0..63
        for (int idx = i; idx < FF * HH; idx += 64) {
            if (fb1[idx] != 0.f) sflags[0] = 0;
            if (fb2[idx] != 0.f) sflags[0] = 0;
        }
        if (i < HH)            { if (rb1[i] != 0.f)      sflags[1] = 0; }
        else                   { if (rb2[i - HH] != 0.f) sflags[1] = 0; }
    }
    __syncthreads();

    // ---- phase 2: q tables ----
    {
        const int f = t >> 2;
        const int og = t & 3;
#pragma unroll
        for (int oo = 0; oo < 8; ++oo) {
            const int o = og * 8 + oo;
            float qp = 0.f, qn = 0.f;
            for (int g = 0; g < HH; ++g) {
                const float w3 = fW3[(f * HH + g) * OO + o];
                qp += fmaxf(vb[0][f][g], 0.f) * w3;
                qn += fminf(vb[1][f][g], 0.f) * w3;
            }
            q_pos[f * OO + o] = qp;
            q_neg[f * OO + o] = qn;
        }
    }
    if (t == 0) { flags[0] = sflags[0]; flags[1] = sflags[1]; }
}

// ---------------------------------------------------------------------------
// Fast f_sums: f_sums[n,o] = qb[o] + sum_f x[n,f] * q_{sign(x)}[f,o]
// 8 nodes per block; thread = (node, o).
// ---------------------------------------------------------------------------
__global__ __launch_bounds__(256) void fsums_fast_kernel(
    const float* __restrict__ x,
    const float* __restrict__ q_pos, const float* __restrict__ q_neg,
    const float* __restrict__ qb, const int* __restrict__ flags,
    float* __restrict__ f_sums)
{
    if (!flags[0]) return;
    __shared__ float xs[8 * FF];
    const int t = threadIdx.x;
    const int n0 = blockIdx.x * 8;

    for (int idx = t; idx < 8 * FF; idx += 256)
        xs[idx] = x[n0 * FF + idx];
    __syncthreads();

    const int r = t >> 5;      // node within block
    const int o = t & 31;
    float acc = qb[o];
#pragma unroll
    for (int f = 0; f < FF; ++f) {
        const float xv = xs[r * FF + f];
        const float qv = (xv >= 0.f) ? q_pos[f * OO + o] : q_neg[f * OO + o];
        acc = fmaf(xv, qv, acc);
    }
    f_sums[(n0 + r) * OO + o] = acc;
}

// ---------------------------------------------------------------------------
// Fast rho+matmul: partial[kb][n][o] = sum_{m in chunk} B[n,m]*f_sums[m,o]
// with B = (c_{sign(d)} * d + rb3) / norm.   512 blocks: 32 row-tiles x 16 k.
// ---------------------------------------------------------------------------
__global__ __launch_bounds__(256) void rho_fast_kernel(
    const float* __restrict__ dmat, const float* __restrict__ norm,
    const float* __restrict__ f_sums,
    const float* __restrict__ cpr, const float* __restrict__ rb3,
    const int* __restrict__ flags,
    float* __restrict__ partial)
{
    if (!flags[1]) return;

    __shared__ float Bt[128 * 66];     // [j][r], padded row stride 66
    __shared__ float fsL[128 * 32];    // [j][o]

    const int t  = threadIdx.x;
    const int rt = blockIdx.x >> 4;    // 0..31
    const int kb = blockIdx.x & 15;    // 0..15
    const int n0 = rt * ROWT;
    const int m0 = kb * 128;

    const float cp = cpr[0], cn = cpr[1], b3 = rb3[0];

    // stage f_sums chunk
    for (int idx = t; idx < 128 * OO; idx += 256)
        fsL[idx] = f_sums[m0 * OO + idx];

    // stage B tile: compute (c*d + rb3)/norm
    for (int idx = t; idx < ROWT * 128; idx += 256) {
        const int r = idx >> 7;
        const int j = idx & 127;
        const long g = (long)(n0 + r) * NN + (m0 + j);
        const float dv = dmat[g];
        const float nv = norm[g];
        const float c  = (dv >= 0.f) ? cp : cn;
        Bt[j * 66 + r] = fmaf(c, dv, b3) / nv;
    }
    __syncthreads();

    const int oq = t & 7;          // float4 group of o
    const int rg = t >> 3;         // 0..31
    const int r0 = rg * 2;

    float4 acc0 = make_float4(0.f, 0.f, 0.f, 0.f);
    float4 acc1 = make_float4(0.f, 0.f, 0.f, 0.f);

#pragma unroll 4
    for (int j = 0; j < 128; ++j) {
        const float2 b  = *(const float2*)&Bt[j * 66 + r0];
        const float4 fv = *(const float4*)&fsL[j * 32 + oq * 4];
        acc0.x = fmaf(b.x, fv.x, acc0.x);
        acc0.y = fmaf(b.x, fv.y, acc0.y);
        acc0.z = fmaf(b.x, fv.z, acc0.z);
        acc0.w = fmaf(b.x, fv.w, acc0.w);
        acc1.x = fmaf(b.y, fv.x, acc1.x);
        acc1.y = fmaf(b.y, fv.y, acc1.y);
        acc1.z = fmaf(b.y, fv.z, acc1.z);
        acc1.w = fmaf(b.y, fv.w, acc1.w);
    }

    float* p = &partial[(size_t)kb * (NN * OO) + (size_t)(n0 + r0) * OO + oq * 4];
    *(float4*)p = acc0;
    *(float4*)(p + OO) = acc1;
}

// ---------------------------------------------------------------------------
// Reduce the 16 K-split partials into out.
// ---------------------------------------------------------------------------
__global__ __launch_bounds__(256) void reduce_kernel(
    const float* __restrict__ partial, const int* __restrict__ flags,
    float* __restrict__ out)
{
    if (!flags[1]) return;
    const int i = blockIdx.x * 256 + threadIdx.x;   // 0..65535
    float s = 0.f;
#pragma unroll
    for (int kb = 0; kb < KSPLIT; ++kb)
        s += partial[kb * (NN * OO) + i];
    out[i] = s;
}

// ---------------------------------------------------------------------------
// SLOW FALLBACKS (exact general path; early-exit when fast path is valid)
// ---------------------------------------------------------------------------
__global__ __launch_bounds__(256) void fsums_kernel(
    const float* __restrict__ x,
    const float* __restrict__ fW1, const float* __restrict__ fb1,
    const float* __restrict__ fW2, const float* __restrict__ fb2,
    const float* __restrict__ fW3, const float* __restrict__ fb3,
    const int* __restrict__ flags,
    float* __restrict__ f_sums)
{
    if (flags[0]) return;
    const int wave = threadIdx.x >> 6;
    const int lane = threadIdx.x & 63;
    const int n = blockIdx.x * 4 + wave;
    const int f = lane;

    const float xv = x[n * FF + f];

    float h1[HH];
#pragma unroll
    for (int h = 0; h < HH; ++h)
        h1[h] = fmaxf(xv * fW1[f * HH + h] + fb1[f * HH + h], 0.f);

    float h2[HH];
#pragma unroll
    for (int g = 0; g < HH; ++g) h2[g] = fb2[f * HH + g];
#pragma unroll
    for (int h = 0; h < HH; ++h) {
        const float a = h1[h];
        const float* __restrict__ w = &fW2[(f * HH + h) * HH];
#pragma unroll
        for (int g = 0; g < HH; ++g) h2[g] += a * w[g];
    }
#pragma unroll
    for (int g = 0; g < HH; ++g) h2[g] = fmaxf(h2[g], 0.f);

    float acc[OO];
#pragma unroll
    for (int o = 0; o < OO; ++o) acc[o] = fb3[f * OO + o];
#pragma unroll
    for (int h = 0; h < HH; ++h) {
        const float a = h2[h];
        const float* __restrict__ w = &fW3[(f * HH + h) * OO];
#pragma unroll
        for (int o = 0; o < OO; ++o) acc[o] += a * w[o];
    }

#pragma unroll
    for (int o = 0; o < OO; ++o) {
        float v = acc[o];
#pragma unroll
        for (int off = 32; off >= 1; off >>= 1)
            v += __shfl_xor(v, off, 64);
        acc[o] = v;
    }
    if (lane == 0) {
#pragma unroll
        for (int o = 0; o < OO; ++o)
            f_sums[n * OO + o] = acc[o];
    }
}

__global__ __launch_bounds__(256) void rho_matmul_kernel(
    const float* __restrict__ dmat, const float* __restrict__ norm,
    const float* __restrict__ rW1, const float* __restrict__ rb1,
    const float* __restrict__ rW2, const float* __restrict__ rb2,
    const float* __restrict__ rW3, const float* __restrict__ rb3,
    const float* __restrict__ f_sums, const int* __restrict__ flags,
    float* __restrict__ out)
{
    if (flags[1]) return;
    const int n = blockIdx.x;
    const int t = threadIdx.x;

    float acc[OO];
#pragma unroll
    for (int o = 0; o < OO; ++o) acc[o] = 0.f;

#pragma unroll 1
    for (int m0 = 0; m0 < NN; m0 += 256) {
        const int m = m0 + t;
        const float d = dmat[n * NN + m];

        float h1[HH];
#pragma unroll
        for (int h = 0; h < HH; ++h)
            h1[h] = fmaxf(d * rW1[h] + rb1[h], 0.f);

        float h2[HH];
#pragma unroll
        for (int g = 0; g < HH; ++g) h2[g] = rb2[g];
#pragma unroll
        for (int h = 0; h < HH; ++h) {
            const float a = h1[h];
#pragma unroll
            for (int g = 0; g < HH; ++g) h2[g] += a * rW2[h * HH + g];
        }

        float r = rb3[0];
#pragma unroll
        for (int h = 0; h < HH; ++h)
            r += fmaxf(h2[h], 0.f) * rW3[h];

        r /= norm[n * NN + m];

        const float* __restrict__ fs = &f_sums[m * OO];
#pragma unroll
        for (int o = 0; o < OO; ++o) acc[o] += r * fs[o];
    }

    __shared__ float red[4][OO];
    const int wave = t >> 6;
    const int lane = t & 63;
#pragma unroll
    for (int o = 0; o < OO; ++o) {
        float v = acc[o];
#pragma unroll
        for (int off = 32; off >= 1; off >>= 1)
            v += __shfl_xor(v, off, 64);
        acc[o] = v;
    }
    if (lane == 0) {
#pragma unroll
        for (int o = 0; o < OO; ++o) red[wave][o] = acc[o];
    }
    __syncthreads();
    if (t < OO)
        out[n * OO + t] = red[0][t] + red[1][t] + red[2][t] + red[3][t];
}

extern "C" void kernel_launch(void* const* d_in, const int* in_sizes, int n_in,
                              void* d_out, int out_size, void* d_ws, size_t ws_size,
                              hipStream_t stream) {
    const float* x    = (const float*)d_in[0];
    const float* dmat = (const float*)d_in[1];
    const float* norm = (const float*)d_in[2];
    const float* fW1  = (const float*)d_in[3];
    const float* fb1  = (const float*)d_in[4];
    const float* fW2  = (const float*)d_in[5];
    const float* fb2  = (const float*)d_in[6];
    const float* fW3  = (const float*)d_in[7];
    const float* fb3  = (const float*)d_in[8];
    const float* rW1  = (const float*)d_in[9];
    const float* rb1  = (const float*)d_in[10];
    const float* rW2  = (const float*)d_in[11];
    const float* rb2  = (const float*)d_in[12];
    const float* rW3  = (const float*)d_in[13];
    const float* rb3  = (const float*)d_in[14];

    char* ws = (char*)d_ws;
    float* f_sums  = (float*)(ws + WS_FSUMS);
    float* partial = (float*)(ws + WS_PARTIAL);
    float* q_pos   = (float*)(ws + WS_QPOS);
    float* q_neg   = (float*)(ws + WS_QNEG);
    float* qb      = (float*)(ws + WS_QB);
    float* cpr     = (float*)(ws + WS_CPR);
    int*   flags   = (int*)(ws + WS_FLAGS);

    float* out = (float*)d_out;

    precompute_kernel<<<1, 256, 0, stream>>>(fW1, fb1, fW2, fb2, fW3, fb3,
                                             rW1, rb1, rW2, rb2, rW3,
                                             q_pos, q_neg, qb, cpr, flags);

    fsums_fast_kernel<<<NN / 8, 256, 0, stream>>>(x, q_pos, q_neg, qb, flags,
                                                  f_sums);
    fsums_kernel<<<NN / 4, 256, 0, stream>>>(x, fW1, fb1, fW2, fb2, fW3, fb3,
                                             flags, f_sums);

    rho_fast_kernel<<<32 * KSPLIT, 256, 0, stream>>>(dmat, norm, f_sums,
                                                     cpr, rb3, flags, partial);
    reduce_kernel<<<NN * OO / 256, 256, 0, stream>>>(partial, flags, out);

    rho_matmul_kernel<<<NN, 256, 0, stream>>>(dmat, norm, rW1, rb1, rW2, rb2,
                                              rW3, rb3, f_sums, flags, out);
}

// Round 3
// 135.736 us; speedup vs baseline: 4.4575x; 1.2663x over previous
//
#include <hip/hip_runtime.h>

#define NN 2048
#define FF 64
#define HH 32
#define OO 32

// Workspace layout (bytes):
//   0        : f_sums       [2048*32] f32   (256 KB)
//   262144   : partial      [16*2048*32] f32 (4 MB)
//   4456448  : q_pos        [64*32] f32
//   4464640  : q_neg        [64*32] f32
//   4472832  : qb           [32] f32        (sum_f fb3[f,:])
//   4472960  : cpr          [2] f32         (c_plus, c_minus)
//   4472976  : flags        [2] int         (fb-zero, rb-zero)
#define WS_FSUMS   0
#define WS_PARTIAL 262144
#define WS_QPOS    4456448
#define WS_QNEG    4464640
#define WS_QB      4472832
#define WS_CPR     4472960
#define WS_FLAGS   4472976

#define KSPLIT 16   // K-chunks of 128 m each
#define ROWT   64   // rows per block in rho_fast

// ---------------------------------------------------------------------------
// Precompute A: per-feature q tables. Grid = 64 blocks (one per feature),
// 64 threads each. Replaces the single-block latency-bound version (45 us).
//   v_s[g]   = sum_h clamp_s(fW1[f,h]) * fW2[f,h,g]
//   q_s[f,o] = sum_g clamp_s(v_s[g])   * fW3[f,g,o]
// ---------------------------------------------------------------------------
__global__ __launch_bounds__(64) void precompute_q_kernel(
    const float* __restrict__ fW1,
    const float* __restrict__ fW2,
    const float* __restrict__ fW3,
    float* __restrict__ q_pos, float* __restrict__ q_neg)
{
    __shared__ float vs[2][HH];
    const int f = blockIdx.x;
    const int t = threadIdx.x;     // 0..63
    const int s = t >> 5;          // 0 = pos, 1 = neg
    const int g = t & 31;

    float v = 0.f;
    for (int h = 0; h < HH; ++h) {
        const float w1 = fW1[f * HH + h];
        const float a = s ? fminf(w1, 0.f) : fmaxf(w1, 0.f);
        v = fmaf(a, fW2[(f * HH + h) * HH + g], v);
    }
    vs[s][g] = s ? fminf(v, 0.f) : fmaxf(v, 0.f);
    __syncthreads();

    const int o = g;
    float q = 0.f;
    for (int gg = 0; gg < HH; ++gg)
        q = fmaf(vs[s][gg], fW3[(f * HH + gg) * OO + o], q);
    if (s) q_neg[f * OO + o] = q;
    else   q_pos[f * OO + o] = q;
}

// ---------------------------------------------------------------------------
// Precompute B: cpr (rho's exact slopes), qb, zero-bias flags.
// One block, 256 threads — touches only ~28 KB, so latency is fine.
// ---------------------------------------------------------------------------
__global__ __launch_bounds__(256) void precompute_misc_kernel(
    const float* __restrict__ fb1, const float* __restrict__ fb2,
    const float* __restrict__ fb3,
    const float* __restrict__ rW1, const float* __restrict__ rb1,
    const float* __restrict__ rW2, const float* __restrict__ rb2,
    const float* __restrict__ rW3,
    float* __restrict__ qb, float* __restrict__ cpr,
    int* __restrict__ flags)
{
    __shared__ float vs[2][HH];
    __shared__ int sflags[2];
    const int t = threadIdx.x;

    if (t == 0) { sflags[0] = 1; sflags[1] = 1; }
    __syncthreads();

    if (t < 64) {
        // v_s[g] for rho
        const int s = t >> 5;
        const int g = t & 31;
        float v = 0.f;
        for (int h = 0; h < HH; ++h) {
            const float w1 = rW1[h];
            const float a = s ? fminf(w1, 0.f) : fmaxf(w1, 0.f);
            v = fmaf(a, rW2[h * HH + g], v);
        }
        vs[s][g] = s ? fminf(v, 0.f) : fmaxf(v, 0.f);
    } else if (t >= 64 && t < 96) {
        // qb[o] = sum_f fb3[f,o]
        const int o = t - 64;
        float a = 0.f;
        for (int f = 0; f < FF; ++f) a += fb3[f * OO + o];
        qb[o] = a;
    } else if (t >= 128 && t < 192) {
        // fb1/fb2 zero scan (FF*HH = 2048 each)
        const int i = t - 128;
        bool bad = false;
        for (int idx = i; idx < FF * HH; idx += 64)
            bad |= (fb1[idx] != 0.f) | (fb2[idx] != 0.f);
        if (bad) sflags[0] = 0;
    } else if (t >= 192) {
        const int i = t - 192;
        bool bad = false;
        if (i < HH) bad = (rb1[i] != 0.f);
        else if (i < 2 * HH) bad = (rb2[i - HH] != 0.f);
        if (bad) sflags[1] = 0;
    }
    __syncthreads();

    if (t < 2) {
        // cp (t==0) / cn (t==1)
        float c = 0.f;
        for (int g = 0; g < HH; ++g)
            c = fmaf(vs[t][g], rW3[g], c);
        cpr[t] = c;
    }
    if (t == 0) { flags[0] = sflags[0]; flags[1] = sflags[1]; }
}

// ---------------------------------------------------------------------------
// Fast f_sums: f_sums[n,o] = qb[o] + sum_f x[n,f] * q_{sign(x)}[f,o]
// ---------------------------------------------------------------------------
__global__ __launch_bounds__(256) void fsums_fast_kernel(
    const float* __restrict__ x,
    const float* __restrict__ q_pos, const float* __restrict__ q_neg,
    const float* __restrict__ qb, const int* __restrict__ flags,
    float* __restrict__ f_sums)
{
    if (!flags[0]) return;
    __shared__ float xs[8 * FF];
    const int t = threadIdx.x;
    const int n0 = blockIdx.x * 8;

    for (int idx = t; idx < 8 * FF; idx += 256)
        xs[idx] = x[n0 * FF + idx];
    __syncthreads();

    const int r = t >> 5;      // node within block
    const int o = t & 31;
    float acc = qb[o];
#pragma unroll
    for (int f = 0; f < FF; ++f) {
        const float xv = xs[r * FF + f];
        const float qv = (xv >= 0.f) ? q_pos[f * OO + o] : q_neg[f * OO + o];
        acc = fmaf(xv, qv, acc);
    }
    f_sums[(n0 + r) * OO + o] = acc;
}

// ---------------------------------------------------------------------------
// Fast rho+matmul: partial[kb][n][o] = sum_{m in chunk} B[n,m]*f_sums[m,o]
// with B = (c_{sign(d)} * d + rb3) / norm.   512 blocks: 32 row-tiles x 16 k.
// ---------------------------------------------------------------------------
__global__ __launch_bounds__(256) void rho_fast_kernel(
    const float* __restrict__ dmat, const float* __restrict__ norm,
    const float* __restrict__ f_sums,
    const float* __restrict__ cpr, const float* __restrict__ rb3,
    const int* __restrict__ flags,
    float* __restrict__ partial)
{
    if (!flags[1]) return;

    __shared__ float Bt[128 * 66];     // [j][r], padded row stride 66
    __shared__ float fsL[128 * 32];    // [j][o]

    const int t  = threadIdx.x;
    const int rt = blockIdx.x >> 4;    // 0..31
    const int kb = blockIdx.x & 15;    // 0..15
    const int n0 = rt * ROWT;
    const int m0 = kb * 128;

    const float cp = cpr[0], cn = cpr[1], b3 = rb3[0];

    for (int idx = t; idx < 128 * OO; idx += 256)
        fsL[idx] = f_sums[m0 * OO + idx];

    for (int idx = t; idx < ROWT * 128; idx += 256) {
        const int r = idx >> 7;
        const int j = idx & 127;
        const long g = (long)(n0 + r) * NN + (m0 + j);
        const float dv = dmat[g];
        const float nv = norm[g];
        const float c  = (dv >= 0.f) ? cp : cn;
        Bt[j * 66 + r] = fmaf(c, dv, b3) / nv;
    }
    __syncthreads();

    const int oq = t & 7;          // float4 group of o
    const int rg = t >> 3;         // 0..31
    const int r0 = rg * 2;

    float4 acc0 = make_float4(0.f, 0.f, 0.f, 0.f);
    float4 acc1 = make_float4(0.f, 0.f, 0.f, 0.f);

#pragma unroll 4
    for (int j = 0; j < 128; ++j) {
        const float2 b  = *(const float2*)&Bt[j * 66 + r0];
        const float4 fv = *(const float4*)&fsL[j * 32 + oq * 4];
        acc0.x = fmaf(b.x, fv.x, acc0.x);
        acc0.y = fmaf(b.x, fv.y, acc0.y);
        acc0.z = fmaf(b.x, fv.z, acc0.z);
        acc0.w = fmaf(b.x, fv.w, acc0.w);
        acc1.x = fmaf(b.y, fv.x, acc1.x);
        acc1.y = fmaf(b.y, fv.y, acc1.y);
        acc1.z = fmaf(b.y, fv.z, acc1.z);
        acc1.w = fmaf(b.y, fv.w, acc1.w);
    }

    float* p = &partial[(size_t)kb * (NN * OO) + (size_t)(n0 + r0) * OO + oq * 4];
    *(float4*)p = acc0;
    *(float4*)(p + OO) = acc1;
}

// ---------------------------------------------------------------------------
// Reduce the 16 K-split partials into out.
// ---------------------------------------------------------------------------
__global__ __launch_bounds__(256) void reduce_kernel(
    const float* __restrict__ partial, const int* __restrict__ flags,
    float* __restrict__ out)
{
    if (!flags[1]) return;
    const int i = blockIdx.x * 256 + threadIdx.x;   // 0..65535
    float s = 0.f;
#pragma unroll
    for (int kb = 0; kb < KSPLIT; ++kb)
        s += partial[kb * (NN * OO) + i];
    out[i] = s;
}

// ---------------------------------------------------------------------------
// SLOW FALLBACKS (exact general path; early-exit when fast path is valid)
// ---------------------------------------------------------------------------
__global__ __launch_bounds__(256) void fsums_kernel(
    const float* __restrict__ x,
    const float* __restrict__ fW1, const float* __restrict__ fb1,
    const float* __restrict__ fW2, const float* __restrict__ fb2,
    const float* __restrict__ fW3, const float* __restrict__ fb3,
    const int* __restrict__ flags,
    float* __restrict__ f_sums)
{
    if (flags[0]) return;
    const int wave = threadIdx.x >> 6;
    const int lane = threadIdx.x & 63;
    const int n = blockIdx.x * 4 + wave;
    const int f = lane;

    const float xv = x[n * FF + f];

    float h1[HH];
#pragma unroll
    for (int h = 0; h < HH; ++h)
        h1[h] = fmaxf(xv * fW1[f * HH + h] + fb1[f * HH + h], 0.f);

    float h2[HH];
#pragma unroll
    for (int g = 0; g < HH; ++g) h2[g] = fb2[f * HH + g];
#pragma unroll
    for (int h = 0; h < HH; ++h) {
        const float a = h1[h];
        const float* __restrict__ w = &fW2[(f * HH + h) * HH];
#pragma unroll
        for (int g = 0; g < HH; ++g) h2[g] += a * w[g];
    }
#pragma unroll
    for (int g = 0; g < HH; ++g) h2[g] = fmaxf(h2[g], 0.f);

    float acc[OO];
#pragma unroll
    for (int o = 0; o < OO; ++o) acc[o] = fb3[f * OO + o];
#pragma unroll
    for (int h = 0; h < HH; ++h) {
        const float a = h2[h];
        const float* __restrict__ w = &fW3[(f * HH + h) * OO];
#pragma unroll
        for (int o = 0; o < OO; ++o) acc[o] += a * w[o];
    }

#pragma unroll
    for (int o = 0; o < OO; ++o) {
        float v = acc[o];
#pragma unroll
        for (int off = 32; off >= 1; off >>= 1)
            v += __shfl_xor(v, off, 64);
        acc[o] = v;
    }
    if (lane == 0) {
#pragma unroll
        for (int o = 0; o < OO; ++o)
            f_sums[n * OO + o] = acc[o];
    }
}

__global__ __launch_bounds__(256) void rho_matmul_kernel(
    const float* __restrict__ dmat, const float* __restrict__ norm,
    const float* __restrict__ rW1, const float* __restrict__ rb1,
    const float* __restrict__ rW2, const float* __restrict__ rb2,
    const float* __restrict__ rW3, const float* __restrict__ rb3,
    const float* __restrict__ f_sums, const int* __restrict__ flags,
    float* __restrict__ out)
{
    if (flags[1]) return;
    const int n = blockIdx.x;
    const int t = threadIdx.x;

    float acc[OO];
#pragma unroll
    for (int o = 0; o < OO; ++o) acc[o] = 0.f;

#pragma unroll 1
    for (int m0 = 0; m0 < NN; m0 += 256) {
        const int m = m0 + t;
        const float d = dmat[n * NN + m];

        float h1[HH];
#pragma unroll
        for (int h = 0; h < HH; ++h)
            h1[h] = fmaxf(d * rW1[h] + rb1[h], 0.f);

        float h2[HH];
#pragma unroll
        for (int g = 0; g < HH; ++g) h2[g] = rb2[g];
#pragma unroll
        for (int h = 0; h < HH; ++h) {
            const float a = h1[h];
#pragma unroll
            for (int g = 0; g < HH; ++g) h2[g] += a * rW2[h * HH + g];
        }

        float r = rb3[0];
#pragma unroll
        for (int h = 0; h < HH; ++h)
            r += fmaxf(h2[h], 0.f) * rW3[h];

        r /= norm[n * NN + m];

        const float* __restrict__ fs = &f_sums[m * OO];
#pragma unroll
        for (int o = 0; o < OO; ++o) acc[o] += r * fs[o];
    }

    __shared__ float red[4][OO];
    const int wave = t >> 6;
    const int lane = t & 63;
#pragma unroll
    for (int o = 0; o < OO; ++o) {
        float v = acc[o];
#pragma unroll
        for (int off = 32; off >= 1; off >>= 1)
            v += __shfl_xor(v, off, 64);
        acc[o] = v;
    }
    if (lane == 0) {
#pragma unroll
        for (int o = 0; o < OO; ++o) red[wave][o] = acc[o];
    }
    __syncthreads();
    if (t < OO)
        out[n * OO + t] = red[0][t] + red[1][t] + red[2][t] + red[3][t];
}

extern "C" void kernel_launch(void* const* d_in, const int* in_sizes, int n_in,
                              void* d_out, int out_size, void* d_ws, size_t ws_size,
                              hipStream_t stream) {
    const float* x    = (const float*)d_in[0];
    const float* dmat = (const float*)d_in[1];
    const float* norm = (const float*)d_in[2];
    const float* fW1  = (const float*)d_in[3];
    const float* fb1  = (const float*)d_in[4];
    const float* fW2  = (const float*)d_in[5];
    const float* fb2  = (const float*)d_in[6];
    const float* fW3  = (const float*)d_in[7];
    const float* fb3  = (const float*)d_in[8];
    const float* rW1  = (const float*)d_in[9];
    const float* rb1  = (const float*)d_in[10];
    const float* rW2  = (const float*)d_in[11];
    const float* rb2  = (const float*)d_in[12];
    const float* rW3  = (const float*)d_in[13];
    const float* rb3  = (const float*)d_in[14];

    char* ws = (char*)d_ws;
    float* f_sums  = (float*)(ws + WS_FSUMS);
    float* partial = (float*)(ws + WS_PARTIAL);
    float* q_pos   = (float*)(ws + WS_QPOS);
    float* q_neg   = (float*)(ws + WS_QNEG);
    float* qb      = (float*)(ws + WS_QB);
    float* cpr     = (float*)(ws + WS_CPR);
    int*   flags   = (int*)(ws + WS_FLAGS);

    float* out = (float*)d_out;

    precompute_q_kernel<<<FF, 64, 0, stream>>>(fW1, fW2, fW3, q_pos, q_neg);
    precompute_misc_kernel<<<1, 256, 0, stream>>>(fb1, fb2, fb3,
                                                  rW1, rb1, rW2, rb2, rW3,
                                                  qb, cpr, flags);

    fsums_fast_kernel<<<NN / 8, 256, 0, stream>>>(x, q_pos, q_neg, qb, flags,
                                                  f_sums);
    fsums_kernel<<<NN / 4, 256, 0, stream>>>(x, fW1, fb1, fW2, fb2, fW3, fb3,
                                             flags, f_sums);

    rho_fast_kernel<<<32 * KSPLIT, 256, 0, stream>>>(dmat, norm, f_sums,
                                                     cpr, rb3, flags, partial);
    reduce_kernel<<<NN * OO / 256, 256, 0, stream>>>(partial, flags, out);

    rho_matmul_kernel<<<NN, 256, 0, stream>>>(dmat, norm, rW1, rb1, rW2, rb2,
                                              rW3, rb3, f_sums, flags, out);
}

// Round 4
// 131.540 us; speedup vs baseline: 4.5997x; 1.0319x over previous
//
#include <hip/hip_runtime.h>

#define NN 2048
#define FF 64
#define HH 32
#define OO 32

// Workspace layout (bytes):
//   0      : f_sums [2048*32] f32  (256 KB)
//   262144 : q_pos  [64*32] f32
//   270336 : q_neg  [64*32] f32
//   278528 : qb     [32] f32
//   278656 : cpr    [2] f32
//   278664 : flags  [2] int
#define WS_FSUMS 0
#define WS_QPOS  262144
#define WS_QNEG  270336
#define WS_QB    278528
#define WS_CPR   278656
#define WS_FLAGS 278664

// ---------------------------------------------------------------------------
// Kernel 1: all precompute. Blocks 0..63: per-feature q tables.
// Block 64: cpr (exact rho slopes), qb, zero-bias flags.
// ---------------------------------------------------------------------------
__global__ __launch_bounds__(256) void precompute_all_kernel(
    const float* __restrict__ fW1, const float* __restrict__ fb1,
    const float* __restrict__ fW2, const float* __restrict__ fb2,
    const float* __restrict__ fW3, const float* __restrict__ fb3,
    const float* __restrict__ rW1, const float* __restrict__ rb1,
    const float* __restrict__ rW2, const float* __restrict__ rb2,
    const float* __restrict__ rW3,
    float* __restrict__ q_pos, float* __restrict__ q_neg,
    float* __restrict__ qb, float* __restrict__ cpr,
    int* __restrict__ flags)
{
    const int t = threadIdx.x;

    if (blockIdx.x < FF) {
        // ---- per-feature q tables ----
        __shared__ float vs[2][HH];
        const int f = blockIdx.x;
        if (t < 64) {
            const int s = t >> 5;      // 0=pos, 1=neg
            const int g = t & 31;
            float v = 0.f;
            for (int h = 0; h < HH; ++h) {
                const float w1 = fW1[f * HH + h];
                const float a = s ? fminf(w1, 0.f) : fmaxf(w1, 0.f);
                v = fmaf(a, fW2[(f * HH + h) * HH + g], v);
            }
            vs[s][g] = s ? fminf(v, 0.f) : fmaxf(v, 0.f);
        }
        __syncthreads();
        if (t < 64) {
            const int s = t >> 5;
            const int o = t & 31;
            float q = 0.f;
            for (int gg = 0; gg < HH; ++gg)
                q = fmaf(vs[s][gg], fW3[(f * HH + gg) * OO + o], q);
            if (s) q_neg[f * OO + o] = q;
            else   q_pos[f * OO + o] = q;
        }
        return;
    }

    // ---- block 64: misc ----
    __shared__ float vsr[2][HH];
    __shared__ int sflags[2];
    if (t == 0) { sflags[0] = 1; sflags[1] = 1; }
    __syncthreads();

    if (t < 64) {
        const int s = t >> 5;
        const int g = t & 31;
        float v = 0.f;
        for (int h = 0; h < HH; ++h) {
            const float w1 = rW1[h];
            const float a = s ? fminf(w1, 0.f) : fmaxf(w1, 0.f);
            v = fmaf(a, rW2[h * HH + g], v);
        }
        vsr[s][g] = s ? fminf(v, 0.f) : fmaxf(v, 0.f);
    } else if (t < 96) {
        const int o = t - 64;
        float a = 0.f;
        for (int f = 0; f < FF; ++f) a += fb3[f * OO + o];
        qb[o] = a;
    } else if (t >= 128 && t < 192) {
        const int i = t - 128;
        bool bad = false;
        for (int idx = i; idx < FF * HH; idx += 64)
            bad |= (fb1[idx] != 0.f) | (fb2[idx] != 0.f);
        if (bad) sflags[0] = 0;
    } else if (t >= 192) {
        const int i = t - 192;
        bool bad = false;
        if (i < HH) bad = (rb1[i] != 0.f);
        else if (i < 2 * HH) bad = (rb2[i - HH] != 0.f);
        if (bad) sflags[1] = 0;
    }
    __syncthreads();

    if (t < 2) {
        float c = 0.f;
        for (int g = 0; g < HH; ++g)
            c = fmaf(vsr[t][g], rW3[g], c);
        cpr[t] = c;
    }
    if (t == 0) { flags[0] = sflags[0]; flags[1] = sflags[1]; }
}

// ---------------------------------------------------------------------------
// Kernel 2: zero out[] + f_sums (fast path or exact fallback). 256 blocks.
// ---------------------------------------------------------------------------
__global__ __launch_bounds__(256) void fsums_all_kernel(
    const float* __restrict__ x,
    const float* __restrict__ q_pos, const float* __restrict__ q_neg,
    const float* __restrict__ qb,
    const float* __restrict__ fW1, const float* __restrict__ fb1,
    const float* __restrict__ fW2, const float* __restrict__ fb2,
    const float* __restrict__ fW3, const float* __restrict__ fb3,
    const int* __restrict__ flags,
    float* __restrict__ f_sums, float* __restrict__ out)
{
    const int t = threadIdx.x;
    // zero the output accumulator (rho_all atomically adds into it)
    out[blockIdx.x * 256 + t] = 0.f;

    const int n0 = blockIdx.x * 8;

    if (flags[0]) {
        __shared__ float xs[8 * FF];
        for (int idx = t; idx < 8 * FF; idx += 256)
            xs[idx] = x[n0 * FF + idx];
        __syncthreads();

        const int r = t >> 5;
        const int o = t & 31;
        float acc = qb[o];
#pragma unroll
        for (int f = 0; f < FF; ++f) {
            const float xv = xs[r * FF + f];
            const float qv = (xv >= 0.f) ? q_pos[f * OO + o] : q_neg[f * OO + o];
            acc = fmaf(xv, qv, acc);
        }
        f_sums[(n0 + r) * OO + o] = acc;
        return;
    }

    // ---- exact fallback: wave-per-node, 2 passes ----
    const int wave = t >> 6;
    const int lane = t & 63;
    for (int pass = 0; pass < 2; ++pass) {
        const int n = n0 + pass * 4 + wave;
        const int f = lane;
        const float xv = x[n * FF + f];

        float h1[HH];
#pragma unroll
        for (int h = 0; h < HH; ++h)
            h1[h] = fmaxf(xv * fW1[f * HH + h] + fb1[f * HH + h], 0.f);

        float h2[HH];
#pragma unroll
        for (int g = 0; g < HH; ++g) h2[g] = fb2[f * HH + g];
#pragma unroll
        for (int h = 0; h < HH; ++h) {
            const float a = h1[h];
            const float* __restrict__ w = &fW2[(f * HH + h) * HH];
#pragma unroll
            for (int g = 0; g < HH; ++g) h2[g] += a * w[g];
        }
#pragma unroll
        for (int g = 0; g < HH; ++g) h2[g] = fmaxf(h2[g], 0.f);

        float acc[OO];
#pragma unroll
        for (int o = 0; o < OO; ++o) acc[o] = fb3[f * OO + o];
#pragma unroll
        for (int h = 0; h < HH; ++h) {
            const float a = h2[h];
            const float* __restrict__ w = &fW3[(f * HH + h) * OO];
#pragma unroll
            for (int o = 0; o < OO; ++o) acc[o] += a * w[o];
        }

#pragma unroll
        for (int o = 0; o < OO; ++o) {
            float v = acc[o];
#pragma unroll
            for (int off = 32; off >= 1; off >>= 1)
                v += __shfl_xor(v, off, 64);
            acc[o] = v;
        }
        if (lane == 0) {
#pragma unroll
            for (int o = 0; o < OO; ++o)
                f_sums[n * OO + o] = acc[o];
        }
    }
}

// ---------------------------------------------------------------------------
// Kernel 3: rho + normalize + matmul. 512 blocks (32 row-tiles x 16 k-splits),
// fast path atomically accumulates into pre-zeroed out. Fallback: 4 rows per
// block, full-K, exact MLP.
// ---------------------------------------------------------------------------
__global__ __launch_bounds__(256) void rho_all_kernel(
    const float* __restrict__ dmat, const float* __restrict__ norm,
    const float* __restrict__ f_sums,
    const float* __restrict__ cpr, const float* __restrict__ rb3,
    const float* __restrict__ rW1, const float* __restrict__ rb1,
    const float* __restrict__ rW2, const float* __restrict__ rb2,
    const float* __restrict__ rW3,
    const int* __restrict__ flags,
    float* __restrict__ out)
{
    const int t = threadIdx.x;

    if (flags[1]) {
        __shared__ float Bt[128 * 66];   // [j][r], padded stride 66
        __shared__ float fsL[128 * 32];  // [j][o]

        const int rt = blockIdx.x >> 4;  // 0..31
        const int kb = blockIdx.x & 15;  // 0..15
        const int n0 = rt * 64;
        const int m0 = kb * 128;

        const float cp = cpr[0], cn = cpr[1], b3 = rb3[0];

        for (int idx = t; idx < 128 * OO; idx += 256)
            fsL[idx] = f_sums[m0 * OO + idx];

        for (int idx = t; idx < 64 * 128; idx += 256) {
            const int r = idx >> 7;
            const int j = idx & 127;
            const long g = (long)(n0 + r) * NN + (m0 + j);
            const float dv = dmat[g];
            const float nv = norm[g];
            const float c  = (dv >= 0.f) ? cp : cn;
            Bt[j * 66 + r] = fmaf(c, dv, b3) / nv;
        }
        __syncthreads();

        const int oq = t & 7;
        const int rg = t >> 3;
        const int r0 = rg * 2;

        float4 acc0 = make_float4(0.f, 0.f, 0.f, 0.f);
        float4 acc1 = make_float4(0.f, 0.f, 0.f, 0.f);

#pragma unroll 4
        for (int j = 0; j < 128; ++j) {
            const float2 b  = *(const float2*)&Bt[j * 66 + r0];
            const float4 fv = *(const float4*)&fsL[j * 32 + oq * 4];
            acc0.x = fmaf(b.x, fv.x, acc0.x);
            acc0.y = fmaf(b.x, fv.y, acc0.y);
            acc0.z = fmaf(b.x, fv.z, acc0.z);
            acc0.w = fmaf(b.x, fv.w, acc0.w);
            acc1.x = fmaf(b.y, fv.x, acc1.x);
            acc1.y = fmaf(b.y, fv.y, acc1.y);
            acc1.z = fmaf(b.y, fv.z, acc1.z);
            acc1.w = fmaf(b.y, fv.w, acc1.w);
        }

        float* p = &out[(n0 + r0) * OO + oq * 4];
        atomicAdd(p + 0, acc0.x);
        atomicAdd(p + 1, acc0.y);
        atomicAdd(p + 2, acc0.z);
        atomicAdd(p + 3, acc0.w);
        atomicAdd(p + OO + 0, acc1.x);
        atomicAdd(p + OO + 1, acc1.y);
        atomicAdd(p + OO + 2, acc1.z);
        atomicAdd(p + OO + 3, acc1.w);
        return;
    }

    // ---- exact fallback: 4 rows per block, full K ----
    __shared__ float red[4][OO];
    const int wave = t >> 6;
    const int lane = t & 63;

    for (int rr = 0; rr < 4; ++rr) {
        const int n = blockIdx.x * 4 + rr;

        float acc[OO];
#pragma unroll
        for (int o = 0; o < OO; ++o) acc[o] = 0.f;

#pragma unroll 1
        for (int m0 = 0; m0 < NN; m0 += 256) {
            const int m = m0 + t;
            const float d = dmat[(long)n * NN + m];

            float h1[HH];
#pragma unroll
            for (int h = 0; h < HH; ++h)
                h1[h] = fmaxf(d * rW1[h] + rb1[h], 0.f);

            float h2[HH];
#pragma unroll
            for (int g = 0; g < HH; ++g) h2[g] = rb2[g];
#pragma unroll
            for (int h = 0; h < HH; ++h) {
                const float a = h1[h];
#pragma unroll
                for (int g = 0; g < HH; ++g) h2[g] += a * rW2[h * HH + g];
            }

            float r = rb3[0];
#pragma unroll
            for (int h = 0; h < HH; ++h)
                r += fmaxf(h2[h], 0.f) * rW3[h];

            r /= norm[(long)n * NN + m];

            const float* __restrict__ fs = &f_sums[m * OO];
#pragma unroll
            for (int o = 0; o < OO; ++o) acc[o] += r * fs[o];
        }

#pragma unroll
        for (int o = 0; o < OO; ++o) {
            float v = acc[o];
#pragma unroll
            for (int off = 32; off >= 1; off >>= 1)
                v += __shfl_xor(v, off, 64);
            acc[o] = v;
        }
        if (lane == 0) {
#pragma unroll
            for (int o = 0; o < OO; ++o) red[wave][o] = acc[o];
        }
        __syncthreads();
        if (t < OO)
            out[n * OO + t] = red[0][t] + red[1][t] + red[2][t] + red[3][t];
        __syncthreads();
    }
}

extern "C" void kernel_launch(void* const* d_in, const int* in_sizes, int n_in,
                              void* d_out, int out_size, void* d_ws, size_t ws_size,
                              hipStream_t stream) {
    const float* x    = (const float*)d_in[0];
    const float* dmat = (const float*)d_in[1];
    const float* norm = (const float*)d_in[2];
    const float* fW1  = (const float*)d_in[3];
    const float* fb1  = (const float*)d_in[4];
    const float* fW2  = (const float*)d_in[5];
    const float* fb2  = (const float*)d_in[6];
    const float* fW3  = (const float*)d_in[7];
    const float* fb3  = (const float*)d_in[8];
    const float* rW1  = (const float*)d_in[9];
    const float* rb1  = (const float*)d_in[10];
    const float* rW2  = (const float*)d_in[11];
    const float* rb2  = (const float*)d_in[12];
    const float* rW3  = (const float*)d_in[13];
    const float* rb3  = (const float*)d_in[14];

    char* ws = (char*)d_ws;
    float* f_sums = (float*)(ws + WS_FSUMS);
    float* q_pos  = (float*)(ws + WS_QPOS);
    float* q_neg  = (float*)(ws + WS_QNEG);
    float* qb     = (float*)(ws + WS_QB);
    float* cpr    = (float*)(ws + WS_CPR);
    int*   flags  = (int*)(ws + WS_FLAGS);

    float* out = (float*)d_out;

    precompute_all_kernel<<<FF + 1, 256, 0, stream>>>(
        fW1, fb1, fW2, fb2, fW3, fb3, rW1, rb1, rW2, rb2, rW3,
        q_pos, q_neg, qb, cpr, flags);

    fsums_all_kernel<<<NN / 8, 256, 0, stream>>>(
        x, q_pos, q_neg, qb, fW1, fb1, fW2, fb2, fW3, fb3, flags,
        f_sums, out);

    rho_all_kernel<<<512, 256, 0, stream>>>(
        dmat, norm, f_sums, cpr, rb3, rW1, rb1, rW2, rb2, rW3, flags, out);
}

// Round 5
// 127.968 us; speedup vs baseline: 4.7281x; 1.0279x over previous
//
#include <hip/hip_runtime.h>

#define NN 2048
#define FF 64
#define HH 32
#define OO 32

// Workspace layout (bytes):
//   0      : f_sums [2048*32] f32  (256 KB)
//   262144 : q_pos  [64*32] f32
//   270336 : q_neg  [64*32] f32
//   278528 : qb     [32] f32
//   278656 : cpr    [2] f32
//   278664 : flags  [2] int
#define WS_FSUMS 0
#define WS_QPOS  262144
#define WS_QNEG  270336
#define WS_QB    278528
#define WS_CPR   278656
#define WS_FLAGS 278664

// ---------------------------------------------------------------------------
// Kernel 1: precompute + zero out.
// Blocks 0..63 (one per feature f): stage fW2/fW3 slabs to LDS with one
// float4/thread, compute q_pos/q_neg[f], and zero a 1024-float chunk of out.
// Block 64: cpr (exact rho slopes), qb, zero-bias flags — all via wide
// cooperative staging (the round-2/4 profiles showed these as serial-latency
// stalls: VALUBusy ~0%, ~45 us).
// ---------------------------------------------------------------------------
__global__ __launch_bounds__(256) void precompute_all_kernel(
    const float* __restrict__ fW1, const float* __restrict__ fb1,
    const float* __restrict__ fW2, const float* __restrict__ fb2,
    const float* __restrict__ fW3, const float* __restrict__ fb3,
    const float* __restrict__ rW1, const float* __restrict__ rb1,
    const float* __restrict__ rW2, const float* __restrict__ rb2,
    const float* __restrict__ rW3,
    float* __restrict__ q_pos, float* __restrict__ q_neg,
    float* __restrict__ qb, float* __restrict__ cpr,
    int* __restrict__ flags, float* __restrict__ out)
{
    __shared__ float sA[HH * HH];      // fW2 slab / rW2
    __shared__ float sB[FF * OO];      // fW3 slab (1024) / fb3 (2048)
    __shared__ float sC[128];          // vs / vsr + small weights
    __shared__ int sflags[2];

    const int t = threadIdx.x;

    if (blockIdx.x < FF) {
        const int f = blockIdx.x;
        // zero 1/64th of out with a float4 store
        ((float4*)out)[blockIdx.x * 256 + t] =
            make_float4(0.f, 0.f, 0.f, 0.f);
        // stage: one float4 per thread per array
        ((float4*)sA)[t] = ((const float4*)&fW2[f * HH * HH])[t];
        ((float4*)sB)[t] = ((const float4*)&fW3[f * HH * OO])[t];
        if (t < HH) sC[64 + t] = fW1[f * HH + t];
        __syncthreads();

        if (t < 64) {
            const int s = t >> 5;      // 0=pos, 1=neg
            const int g = t & 31;
            float v = 0.f;
#pragma unroll
            for (int h = 0; h < HH; ++h) {
                const float w1 = sC[64 + h];
                const float a = s ? fminf(w1, 0.f) : fmaxf(w1, 0.f);
                v = fmaf(a, sA[h * HH + g], v);
            }
            sC[t] = s ? fminf(v, 0.f) : fmaxf(v, 0.f);
        }
        __syncthreads();
        if (t < 64) {
            const int s = t >> 5;
            const int o = t & 31;
            float q = 0.f;
#pragma unroll
            for (int g = 0; g < HH; ++g)
                q = fmaf(sC[s * 32 + g], sB[g * OO + o], q);
            if (s) q_neg[f * OO + o] = q;
            else   q_pos[f * OO + o] = q;
        }
        return;
    }

    // ---- block 64: misc ----
    if (t == 0) { sflags[0] = 1; sflags[1] = 1; }
    // stage rW2 (1024 floats), fb3 (2048 floats), rW1/rW3 (32 each)
    ((float4*)sA)[t] = ((const float4*)rW2)[t];
    ((float4*)sB)[t] = ((const float4*)fb3)[t];
    ((float4*)sB)[t + 256] = ((const float4*)fb3)[t + 256];
    if (t < HH) sC[64 + t] = rW1[t];
    else if (t < 64) sC[96 + (t - HH)] = rW3[t - HH];
    __syncthreads();

    if (t < 64) {
        // vsr for rho slopes
        const int s = t >> 5;
        const int g = t & 31;
        float v = 0.f;
#pragma unroll
        for (int h = 0; h < HH; ++h) {
            const float w1 = sC[64 + h];
            const float a = s ? fminf(w1, 0.f) : fmaxf(w1, 0.f);
            v = fmaf(a, sA[h * HH + g], v);
        }
        sC[t] = s ? fminf(v, 0.f) : fmaxf(v, 0.f);
    } else if (t < 96) {
        // qb[o] = sum_f fb3[f,o] from LDS (bank-parallel column sum)
        const int o = t - 64;
        float a = 0.f;
#pragma unroll
        for (int f = 0; f < FF; ++f) a += sB[f * OO + o];
        qb[o] = a;
    } else if (t < 160) {
        // rb1/rb2 zero scan
        const int i = t - 96;
        bool bad;
        if (i < HH) bad = (rb1[i] != 0.f);
        else        bad = (rb2[i - HH] != 0.f);
        if (bad) sflags[1] = 0;
    } else {
        // fb1/fb2 zero scan, float4-wide (512 float4 each over 96 threads)
        const float4* b1 = (const float4*)fb1;
        const float4* b2 = (const float4*)fb2;
        bool bad = false;
        for (int i = t - 160; i < (FF * HH) / 4; i += 96) {
            const float4 a = b1[i], b = b2[i];
            bad |= (a.x != 0.f) | (a.y != 0.f) | (a.z != 0.f) | (a.w != 0.f);
            bad |= (b.x != 0.f) | (b.y != 0.f) | (b.z != 0.f) | (b.w != 0.f);
        }
        if (bad) sflags[0] = 0;
    }
    __syncthreads();

    if (t < 2) {
        float c = 0.f;
#pragma unroll
        for (int g = 0; g < HH; ++g)
            c = fmaf(sC[t * 32 + g], sC[96 + g], c);
        cpr[t] = c;
    }
    if (t == 0) { flags[0] = sflags[0]; flags[1] = sflags[1]; }
}

// ---------------------------------------------------------------------------
// Kernel 2: f_sums. Fast path: stage q tables (16 KB) + x (2 KB) into LDS
// with float4 cooperative loads, then the 64-f inner loop is pure LDS.
// 256 blocks x 8 nodes.
// ---------------------------------------------------------------------------
__global__ __launch_bounds__(256) void fsums_all_kernel(
    const float* __restrict__ x,
    const float* __restrict__ q_pos, const float* __restrict__ q_neg,
    const float* __restrict__ qb,
    const float* __restrict__ fW1, const float* __restrict__ fb1,
    const float* __restrict__ fW2, const float* __restrict__ fb2,
    const float* __restrict__ fW3, const float* __restrict__ fb3,
    const int* __restrict__ flags,
    float* __restrict__ f_sums)
{
    const int t = threadIdx.x;
    const int n0 = blockIdx.x * 8;

    if (flags[0]) {
        __shared__ float qs[2][FF * OO];   // 2 x 8 KB
        __shared__ float xs[8 * FF];       // 2 KB
        ((float4*)qs[0])[t]       = ((const float4*)q_pos)[t];
        ((float4*)qs[0])[t + 256] = ((const float4*)q_pos)[t + 256];
        ((float4*)qs[1])[t]       = ((const float4*)q_neg)[t];
        ((float4*)qs[1])[t + 256] = ((const float4*)q_neg)[t + 256];
        if (t < 128) ((float4*)xs)[t] = ((const float4*)&x[n0 * FF])[t];
        __syncthreads();

        const int r = t >> 5;
        const int o = t & 31;
        float acc = qb[o];
#pragma unroll
        for (int f = 0; f < FF; ++f) {
            const float xv = xs[r * FF + f];
            const float qv = (xv >= 0.f) ? qs[0][f * OO + o]
                                         : qs[1][f * OO + o];
            acc = fmaf(xv, qv, acc);
        }
        f_sums[(n0 + r) * OO + o] = acc;
        return;
    }

    // ---- exact fallback: wave-per-node, 2 passes ----
    const int wave = t >> 6;
    const int lane = t & 63;
    for (int pass = 0; pass < 2; ++pass) {
        const int n = n0 + pass * 4 + wave;
        const int f = lane;
        const float xv = x[n * FF + f];

        float h1[HH];
#pragma unroll
        for (int h = 0; h < HH; ++h)
            h1[h] = fmaxf(xv * fW1[f * HH + h] + fb1[f * HH + h], 0.f);

        float h2[HH];
#pragma unroll
        for (int g = 0; g < HH; ++g) h2[g] = fb2[f * HH + g];
#pragma unroll
        for (int h = 0; h < HH; ++h) {
            const float a = h1[h];
            const float* __restrict__ w = &fW2[(f * HH + h) * HH];
#pragma unroll
            for (int g = 0; g < HH; ++g) h2[g] += a * w[g];
        }
#pragma unroll
        for (int g = 0; g < HH; ++g) h2[g] = fmaxf(h2[g], 0.f);

        float acc[OO];
#pragma unroll
        for (int o = 0; o < OO; ++o) acc[o] = fb3[f * OO + o];
#pragma unroll
        for (int h = 0; h < HH; ++h) {
            const float a = h2[h];
            const float* __restrict__ w = &fW3[(f * HH + h) * OO];
#pragma unroll
            for (int o = 0; o < OO; ++o) acc[o] += a * w[o];
        }

#pragma unroll
        for (int o = 0; o < OO; ++o) {
            float v = acc[o];
#pragma unroll
            for (int off = 32; off >= 1; off >>= 1)
                v += __shfl_xor(v, off, 64);
            acc[o] = v;
        }
        if (lane == 0) {
#pragma unroll
            for (int o = 0; o < OO; ++o)
                f_sums[n * OO + o] = acc[o];
        }
    }
}

// ---------------------------------------------------------------------------
// Kernel 3: rho + normalize + matmul. 512 blocks (32 row-tiles x 16 k-splits).
// float4 staging of dmat/norm (4x fewer VMEM instrs); atomicAdd into the
// pre-zeroed out. Fallback: exact MLP path.
// ---------------------------------------------------------------------------
__global__ __launch_bounds__(256) void rho_all_kernel(
    const float* __restrict__ dmat, const float* __restrict__ norm,
    const float* __restrict__ f_sums,
    const float* __restrict__ cpr, const float* __restrict__ rb3,
    const float* __restrict__ rW1, const float* __restrict__ rb1,
    const float* __restrict__ rW2, const float* __restrict__ rb2,
    const float* __restrict__ rW3,
    const int* __restrict__ flags,
    float* __restrict__ out)
{
    const int t = threadIdx.x;

    if (flags[1]) {
        __shared__ float Bt[128 * 66];   // [j][r], padded stride 66
        __shared__ float fsL[128 * 32];  // [j][o]

        const int rt = blockIdx.x >> 4;  // 0..31
        const int kb = blockIdx.x & 15;  // 0..15
        const int n0 = rt * 64;
        const int m0 = kb * 128;

        const float cp = cpr[0], cn = cpr[1], b3 = rb3[0];

        // stage f_sums chunk: 1024 float4s
        {
            const float4* src = (const float4*)&f_sums[m0 * OO];
            float4* dst = (float4*)fsL;
#pragma unroll
            for (int i = 0; i < 4; ++i)
                dst[i * 256 + t] = src[i * 256 + t];
        }

        // stage B tile with float4 loads (2048 float4-groups over 8 iters)
#pragma unroll
        for (int it = 0; it < 8; ++it) {
            const int idx4 = it * 256 + t;        // float4-group index
            const int r = idx4 >> 5;              // row within tile
            const int j4 = (idx4 & 31) * 4;       // first j of the group
            const long g = (long)(n0 + r) * NN + (m0 + j4);
            const float4 d4 = *(const float4*)&dmat[g];
            const float4 n4 = *(const float4*)&norm[g];
            Bt[(j4 + 0) * 66 + r] =
                fmaf(d4.x >= 0.f ? cp : cn, d4.x, b3) / n4.x;
            Bt[(j4 + 1) * 66 + r] =
                fmaf(d4.y >= 0.f ? cp : cn, d4.y, b3) / n4.y;
            Bt[(j4 + 2) * 66 + r] =
                fmaf(d4.z >= 0.f ? cp : cn, d4.z, b3) / n4.z;
            Bt[(j4 + 3) * 66 + r] =
                fmaf(d4.w >= 0.f ? cp : cn, d4.w, b3) / n4.w;
        }
        __syncthreads();

        const int oq = t & 7;
        const int rg = t >> 3;
        const int r0 = rg * 2;

        float4 acc0 = make_float4(0.f, 0.f, 0.f, 0.f);
        float4 acc1 = make_float4(0.f, 0.f, 0.f, 0.f);

#pragma unroll 4
        for (int j = 0; j < 128; ++j) {
            const float2 b  = *(const float2*)&Bt[j * 66 + r0];
            const float4 fv = *(const float4*)&fsL[j * 32 + oq * 4];
            acc0.x = fmaf(b.x, fv.x, acc0.x);
            acc0.y = fmaf(b.x, fv.y, acc0.y);
            acc0.z = fmaf(b.x, fv.z, acc0.z);
            acc0.w = fmaf(b.x, fv.w, acc0.w);
            acc1.x = fmaf(b.y, fv.x, acc1.x);
            acc1.y = fmaf(b.y, fv.y, acc1.y);
            acc1.z = fmaf(b.y, fv.z, acc1.z);
            acc1.w = fmaf(b.y, fv.w, acc1.w);
        }

        float* p = &out[(n0 + r0) * OO + oq * 4];
        atomicAdd(p + 0, acc0.x);
        atomicAdd(p + 1, acc0.y);
        atomicAdd(p + 2, acc0.z);
        atomicAdd(p + 3, acc0.w);
        atomicAdd(p + OO + 0, acc1.x);
        atomicAdd(p + OO + 1, acc1.y);
        atomicAdd(p + OO + 2, acc1.z);
        atomicAdd(p + OO + 3, acc1.w);
        return;
    }

    // ---- exact fallback: 4 rows per block, full K ----
    __shared__ float red[4][OO];
    const int wave = t >> 6;
    const int lane = t & 63;

    for (int rr = 0; rr < 4; ++rr) {
        const int n = blockIdx.x * 4 + rr;

        float acc[OO];
#pragma unroll
        for (int o = 0; o < OO; ++o) acc[o] = 0.f;

#pragma unroll 1
        for (int m0 = 0; m0 < NN; m0 += 256) {
            const int m = m0 + t;
            const float d = dmat[(long)n * NN + m];

            float h1[HH];
#pragma unroll
            for (int h = 0; h < HH; ++h)
                h1[h] = fmaxf(d * rW1[h] + rb1[h], 0.f);

            float h2[HH];
#pragma unroll
            for (int g = 0; g < HH; ++g) h2[g] = rb2[g];
#pragma unroll
            for (int h = 0; h < HH; ++h) {
                const float a = h1[h];
#pragma unroll
                for (int g = 0; g < HH; ++g) h2[g] += a * rW2[h * HH + g];
            }

            float r = rb3[0];
#pragma unroll
            for (int h = 0; h < HH; ++h)
                r += fmaxf(h2[h], 0.f) * rW3[h];

            r /= norm[(long)n * NN + m];

            const float* __restrict__ fs = &f_sums[m * OO];
#pragma unroll
            for (int o = 0; o < OO; ++o) acc[o] += r * fs[o];
        }

#pragma unroll
        for (int o = 0; o < OO; ++o) {
            float v = acc[o];
#pragma unroll
            for (int off = 32; off >= 1; off >>= 1)
                v += __shfl_xor(v, off, 64);
            acc[o] = v;
        }
        if (lane == 0) {
#pragma unroll
            for (int o = 0; o < OO; ++o) red[wave][o] = acc[o];
        }
        __syncthreads();
        if (t < OO)
            out[n * OO + t] = red[0][t] + red[1][t] + red[2][t] + red[3][t];
        __syncthreads();
    }
}

extern "C" void kernel_launch(void* const* d_in, const int* in_sizes, int n_in,
                              void* d_out, int out_size, void* d_ws, size_t ws_size,
                              hipStream_t stream) {
    const float* x    = (const float*)d_in[0];
    const float* dmat = (const float*)d_in[1];
    const float* norm = (const float*)d_in[2];
    const float* fW1  = (const float*)d_in[3];
    const float* fb1  = (const float*)d_in[4];
    const float* fW2  = (const float*)d_in[5];
    const float* fb2  = (const float*)d_in[6];
    const float* fW3  = (const float*)d_in[7];
    const float* fb3  = (const float*)d_in[8];
    const float* rW1  = (const float*)d_in[9];
    const float* rb1  = (const float*)d_in[10];
    const float* rW2  = (const float*)d_in[11];
    const float* rb2  = (const float*)d_in[12];
    const float* rW3  = (const float*)d_in[13];
    const float* rb3  = (const float*)d_in[14];

    char* ws = (char*)d_ws;
    float* f_sums = (float*)(ws + WS_FSUMS);
    float* q_pos  = (float*)(ws + WS_QPOS);
    float* q_neg  = (float*)(ws + WS_QNEG);
    float* qb     = (float*)(ws + WS_QB);
    float* cpr    = (float*)(ws + WS_CPR);
    int*   flags  = (int*)(ws + WS_FLAGS);

    float* out = (float*)d_out;

    precompute_all_kernel<<<FF + 1, 256, 0, stream>>>(
        fW1, fb1, fW2, fb2, fW3, fb3, rW1, rb1, rW2, rb2, rW3,
        q_pos, q_neg, qb, cpr, flags, out);

    fsums_all_kernel<<<NN / 8, 256, 0, stream>>>(
        x, q_pos, q_neg, qb, fW1, fb1, fW2, fb2, fW3, fb3, flags, f_sums);

    rho_all_kernel<<<512, 256, 0, stream>>>(
        dmat, norm, f_sums, cpr, rb3, rW1, rb1, rW2, rb2, rW3, flags, out);
}